// Round 10
// baseline (1924.909 us; speedup 1.0000x reference)
//
#include <hip/hip_runtime.h>

#define EPS 1e-05f
#define ALPHA 0.05f

typedef _Float16 h2v __attribute__((ext_vector_type(2)));
typedef _Float16 f16x8 __attribute__((ext_vector_type(8)));
typedef float f32x16 __attribute__((ext_vector_type(16)));

__device__ __forceinline__ float rcp_f(float x){ return __builtin_amdgcn_rcpf(x); }
__device__ __forceinline__ float dot2(h2v a, h2v b, float c){
  return __builtin_amdgcn_fdot2(a, b, c, false);
}
__device__ __forceinline__ h2v uh(uint u){ return __builtin_bit_cast(h2v, u); }
__device__ __forceinline__ float uf(uint u){ return __builtin_bit_cast(float, u); }

#define LOG2E 1.4426950408889634f
#define LN2   0.6931471805599453f

__device__ __forceinline__ float fast_tanh(float x){
  float ax = fabsf(x);
  float e  = exp2f(ax * (-2.0f * LOG2E));
  float t  = (1.0f - e) * rcp_f(1.0f + e);
  return copysignf(t, x);
}
__device__ __forceinline__ float fast_sp(float x){
  float ax = fabsf(x);
  float e  = exp2f(ax * -LOG2E);
  return fmaxf(x, 0.0f) + log2f(1.0f + e) * LN2;
}
__device__ __forceinline__ float fast_sig(float x){
  float ax = fabsf(x);
  float e  = exp2f(ax * -LOG2E);
  float r  = rcp_f(1.0f + e);
  return x >= 0.0f ? r : e * r;
}
__device__ __forceinline__ float sig_from_sp(float sp){
  return 1.0f - exp2f(sp * -LOG2E);
}
__device__ __forceinline__ h2v mkh2(float a, float b){
  h2v r; r.x = (_Float16)a; r.y = (_Float16)b; return r;
}
__device__ __forceinline__ uint packh(float a, float b){
  ushort lo = __builtin_bit_cast(ushort, (_Float16)a);
  ushort hi = __builtin_bit_cast(ushort, (_Float16)b);
  return (uint)lo | ((uint)hi << 16);
}
__device__ __forceinline__ float f16lo(uint u){
  return (float)__builtin_bit_cast(_Float16, (ushort)(u & 0xffffu));
}
__device__ __forceinline__ float f16hi(uint u){
  return (float)__builtin_bit_cast(_Float16, (ushort)(u >> 16));
}

// ================= fused kernel: stage + pack + yref + compute =================
// __launch_bounds__(512, 1): 1 block/CU min -> 8 waves/CU = 2 waves/SIMD ->
// VGPR budget 256. R7's z2-MFMA needed ~137 live regs; at the (512,2) cap of
// 128 it spilled 3.67 GB to scratch (10x slowdown). LDS 73.7 KB caps
// residency at 2 blocks/CU regardless, so the bound costs nothing extra.
__global__ __launch_bounds__(512, 1) void holo_main(
    const float* __restrict__ X, const float* __restrict__ U,
    const float* __restrict__ xref,
    const float* __restrict__ fw1, const float* __restrict__ fb1,
    const float* __restrict__ fw2, const float* __restrict__ fb2,
    const float* __restrict__ fw3, const float* __restrict__ fb3,
    const float* __restrict__ gw,  const float* __restrict__ gb,
    const float* __restrict__ iw1, const float* __restrict__ ib1,
    const float* __restrict__ iw2, const float* __restrict__ ib2,
    const float* __restrict__ iw3, const float* __restrict__ ib3,
    const float* __restrict__ iw4, const float* __restrict__ ib4,
    const float* __restrict__ im2, const float* __restrict__ im3,
    const float* __restrict__ im4,
    float* __restrict__ out, int N)
{
  // ---- LDS (natural layouts, zero-padded; reads use runtime hh offsets) ----
  __shared__ alignas(16) ushort sW2r[224*84]; // fw2 MFMA-A [224 rows][84 halves]
  __shared__ uint4 sW3E[224];   // 112 n-pairs x2: {w3 d0..d5 pairs, fb2[n], fb2[n+1]}
  __shared__ alignas(16) ushort sA2[64*68];   // iw2 MFMA-A [64 rows j][68 halves k]
  __shared__ uint4 sPW1B[80];   // fw1 row o: {w01,w23,w45, fb1[o]}
  __shared__ uint4 sPGB[36];    // gw  row o: {w01,w23,w45, gb[o]}
  __shared__ uint4 sPI1B[60];   // iw1 rows: {w,b} pairs
  __shared__ uint4 sPI1C[60];   // iw1^T pairs [30 kp][6 d + pad]
  __shared__ uint4 sPI3[240];   // iw3 [30 i3][32 jp] (jp 30,31 = 0)
  __shared__ uint4 sPI3C[256];  // iw3^T [64 j][16 qp] (rows 60-63, qp 15 = 0)
  __shared__ uint4 sPM2B[64];   // im2 row j: {w01,w23,w45, ib2[j]} (rows 60-63 = 0)
  __shared__ uint4 sPM2C[64];   // im2^T [32 jp][8] (jp 30,31 = 0)
  __shared__ uint4 sPM3B[60];   // im3 rows: {w,ib3 | iw4,0,0,0}
  __shared__ uint4 sPM3C[30];   // im3^T [15 qp][8]
  __shared__ uint  sPM4u[4];    // im4 pairs
  __shared__ alignas(16) uint sPI2Cu[60*32]; // iw2^T [60 k1][32 jp] (jp 30,31 = 0)
  __shared__ float sFB3[6], sXREF[6], sIM4[6];
  __shared__ float sS1[60], sS2[60], sS3[30];
  __shared__ float sYREF, sIB4;

  const int t = threadIdx.x;
  const int T = 512;
  const int lane = t & 63;
  const int hh  = lane >> 5;
  const int l31 = lane & 31;

  // ---- stage + pack from original weights ----
  for (int idx=t; idx<224*42; idx+=T){
    int row = idx/42, c = idx%42, k = 2*c;
    uint v = 0;
    if (row < 200 && k < 80) v = packh(fw2[row*80+k], fw2[row*80+k+1]);
    ((uint*)sW2r)[idx] = v;
  }
  for (int idx=t; idx<896; idx+=T){
    int P = idx/8, c = idx%8, n = 2*P;
    uint v = 0;
    if (n < 200){
      if (c < 6)       v = packh(fw3[c*200+n], fw3[c*200+n+1]);
      else if (c == 6) v = __builtin_bit_cast(uint, fb2[n]);
      else             v = __builtin_bit_cast(uint, fb2[n+1]);
    }
    ((uint*)sW3E)[idx] = v;
  }
  for (int idx=t; idx<64*34; idx+=T){           // sA2
    int row = idx/34, c = idx%34, k = 2*c;
    uint v = 0;
    if (row < 60 && c < 30) v = packh(iw2[row*60+k], iw2[row*60+k+1]);
    ((uint*)sA2)[idx] = v;
  }
  for (int idx=t; idx<320; idx+=T){
    int o = idx/4, c = idx%4;
    ((uint*)sPW1B)[idx] = (c<3) ? packh(fw1[o*6+2*c], fw1[o*6+2*c+1])
                                : __builtin_bit_cast(uint, fb1[o]);
  }
  for (int idx=t; idx<144; idx+=T){
    int o = idx/4, c = idx%4;
    ((uint*)sPGB)[idx] = (c<3) ? packh(gw[o*6+2*c], gw[o*6+2*c+1])
                               : __builtin_bit_cast(uint, gb[o]);
  }
  for (int idx=t; idx<240; idx+=T){
    int p = idx/8, c = idx%8, sub = c/4, cc = c%4, nr = 2*p+sub;
    ((uint*)sPI1B)[idx] = (cc<3) ? packh(iw1[nr*6+2*cc], iw1[nr*6+2*cc+1])
                                 : __builtin_bit_cast(uint, ib1[nr]);
  }
  for (int idx=t; idx<240; idx+=T){
    int q = idx/8, c = idx%8;
    ((uint*)sPI1C)[idx] = (c<6) ? packh(iw1[(2*q)*6+c], iw1[(2*q+1)*6+c]) : 0u;
  }
  for (int idx=t; idx<960; idx+=T){
    int r = idx/32, q = idx%32;
    ((uint*)sPI3)[idx] = (q<30) ? packh(iw3[r*60+2*q], iw3[r*60+2*q+1]) : 0u;
  }
  for (int idx=t; idx<1024; idx+=T){
    int j = idx/16, q = idx%16;
    ((uint*)sPI3C)[idx] = (j<60 && q<15) ? packh(iw3[(2*q)*60+j], iw3[(2*q+1)*60+j]) : 0u;
  }
  for (int idx=t; idx<256; idx+=T){
    int j = idx/4, c = idx%4;
    uint v = 0;
    if (j < 60) v = (c<3) ? packh(im2[j*6+2*c], im2[j*6+2*c+1])
                          : __builtin_bit_cast(uint, ib2[j]);
    ((uint*)sPM2B)[idx] = v;
  }
  for (int idx=t; idx<256; idx+=T){
    int q = idx/8, c = idx%8;
    ((uint*)sPM2C)[idx] = (q<30 && c<6) ? packh(im2[(2*q)*6+c], im2[(2*q+1)*6+c]) : 0u;
  }
  for (int idx=t; idx<240; idx+=T){
    int r = idx/8, c = idx%8;
    uint v = 0;
    if (c < 3)       v = packh(im3[r*6+2*c], im3[r*6+2*c+1]);
    else if (c == 3) v = __builtin_bit_cast(uint, ib3[r]);
    else if (c == 4) v = __builtin_bit_cast(uint, iw4[r]);
    ((uint*)sPM3B)[idx] = v;
  }
  for (int idx=t; idx<120; idx+=T){
    int q = idx/8, c = idx%8;
    ((uint*)sPM3C)[idx] = (c<6) ? packh(im3[(2*q)*6+c], im3[(2*q+1)*6+c]) : 0u;
  }
  for (int idx=t; idx<4; idx+=T)
    sPM4u[idx] = (idx<3) ? packh(im4[2*idx], im4[2*idx+1]) : 0u;
  for (int idx=t; idx<1920; idx+=T){
    int k1 = idx/32, q = idx%32;
    sPI2Cu[idx] = (q<30) ? packh(iw2[(2*q)*60+k1], iw2[(2*q+1)*60+k1]) : 0u;
  }
  for (int k=t;k<6;k+=T){ sFB3[k]=fb3[k]; sIM4[k]=im4[k]; sXREF[k]=xref[k]; }
  if (t==0) sIB4=ib4[0];
  __syncthreads();

  // ---- cooperative yref = icnn(xref) from the SAME packed f16 weights ----
  {
    h2v xrp[3];
    #pragma unroll
    for (int p = 0; p < 3; p++) xrp[p] = mkh2(sXREF[2*p], sXREF[2*p+1]);
    if (t < 60){
      const uint* w = (const uint*)sPI1B + (t/2)*8 + (t&1)*4;
      float z = uf(w[3]);
      #pragma unroll
      for (int c = 0; c < 3; c++) z = dot2(uh(w[c]), xrp[c], z);
      sS1[t] = fast_sp(z);
    }
    __syncthreads();
    if (t < 60){
      const uint* m = (const uint*)sPM2B + t*4;
      float z = uf(m[3]);
      #pragma unroll
      for (int c = 0; c < 3; c++) z = dot2(uh(m[c]), xrp[c], z);
      const uint* arow = (const uint*)sA2 + t*34;
      for (int q = 0; q < 30; q++)
        z = dot2(uh(arow[q]), mkh2(sS1[2*q], sS1[2*q+1]), z);
      sS2[t] = fast_sp(z);
    }
    __syncthreads();
    if (t < 30){
      const uint* m = (const uint*)sPM3B + t*8;
      float z = uf(m[3]);
      #pragma unroll
      for (int c = 0; c < 3; c++) z = dot2(uh(m[c]), xrp[c], z);
      const uint* prow = (const uint*)sPI3 + t*32;
      for (int q = 0; q < 30; q++)
        z = dot2(uh(prow[q]), mkh2(sS2[2*q], sS2[2*q+1]), z);
      sS3[t] = fast_sp(z);
    }
    __syncthreads();
    if (t == 0){
      float y = sIB4;
      #pragma unroll
      for (int p = 0; p < 3; p++) y = dot2(uh(sPM4u[p]), xrp[p], y);
      for (int j = 0; j < 30; j++) y = fmaf(uf(((const uint*)sPM3B)[j*8+4]), sS3[j], y);
      sYREF = y;
    }
    __syncthreads();
  }

  // ---- per-thread sample compute (guarded loads/stores, full-wave execution) ----
  const int i = blockIdx.x * blockDim.x + t;
  const bool valid = (i < N);

  float x[6]; h2v xp[3];
  #pragma unroll
  for (int k = 0; k < 6; k++) x[k] = valid ? X[(long)i*6 + k] : 0.0f;
  #pragma unroll
  for (int p = 0; p < 3; p++) xp[p] = mkh2(x[2*p], x[2*p+1]);

  // ============ FNN layer 1: 6 -> 80, tanh ============
  uint h1u[40];
  #pragma unroll
  for (int o = 0; o < 80; o += 2){
    uint4 wa = sPW1B[o], wb = sPW1B[o+1];
    float z0 = uf(wa.w), z1 = uf(wb.w);
    z0 = dot2(uh(wa.x), xp[0], z0); z0 = dot2(uh(wa.y), xp[1], z0); z0 = dot2(uh(wa.z), xp[2], z0);
    z1 = dot2(uh(wb.x), xp[0], z1); z1 = dot2(uh(wb.y), xp[1], z1); z1 = dot2(uh(wb.z), xp[2], z1);
    h1u[o/2] = packh(fast_tanh(z0), fast_tanh(z1));
  }

  // ============ FNN L2+L3 via MFMA (32x32x16 f16) ============
  uint bf0[5][4], bf1[5][4];
  {
    int a0 = 4 * l31;
    int a1 = 4 * (32 + l31);
    #pragma unroll
    for (int kt = 0; kt < 5; kt++){
      #pragma unroll
      for (int q = 0; q < 4; q++){
        int lo0 = __builtin_amdgcn_ds_bpermute(a0, (int)h1u[kt*8 + q]);
        int hi0 = __builtin_amdgcn_ds_bpermute(a0, (int)h1u[kt*8 + 4 + q]);
        bf0[kt][q] = hh ? (uint)hi0 : (uint)lo0;
        int lo1 = __builtin_amdgcn_ds_bpermute(a1, (int)h1u[kt*8 + q]);
        int hi1 = __builtin_amdgcn_ds_bpermute(a1, (int)h1u[kt*8 + 4 + q]);
        bf1[kt][q] = hh ? (uint)hi1 : (uint)lo1;
      }
    }
  }

  float fp0[6] = {0.f,0.f,0.f,0.f,0.f,0.f};
  float fp1[6] = {0.f,0.f,0.f,0.f,0.f,0.f};
  for (int mt = 0; mt < 7; mt++){
    const int row = mt*32 + l31;
    f16x8 af[5];
    #pragma unroll
    for (int kt = 0; kt < 5; kt++){
      const ushort* wp = &sW2r[row*84 + kt*16 + 8*hh];
      uint2 w0 = *(const uint2*)wp;
      uint2 w1 = *(const uint2*)(wp + 4);
      uint4 au; au.x = w0.x; au.y = w0.y; au.z = w1.x; au.w = w1.y;
      af[kt] = __builtin_bit_cast(f16x8, au);
    }
    f32x16 acc0 = {0,0,0,0,0,0,0,0,0,0,0,0,0,0,0,0};
    f32x16 acc1 = {0,0,0,0,0,0,0,0,0,0,0,0,0,0,0,0};
    #pragma unroll
    for (int kt = 0; kt < 5; kt++){
      uint4 b0u; b0u.x=bf0[kt][0]; b0u.y=bf0[kt][1]; b0u.z=bf0[kt][2]; b0u.w=bf0[kt][3];
      uint4 b1u; b1u.x=bf1[kt][0]; b1u.y=bf1[kt][1]; b1u.z=bf1[kt][2]; b1u.w=bf1[kt][3];
      acc0 = __builtin_amdgcn_mfma_f32_32x32x16_f16(af[kt], __builtin_bit_cast(f16x8, b0u), acc0, 0, 0, 0);
      acc1 = __builtin_amdgcn_mfma_f32_32x32x16_f16(af[kt], __builtin_bit_cast(f16x8, b1u), acc1, 0, 0, 0);
    }
    // epilogue (neuron pairs); rows 200-223 are zero-pad -> mt==6 keeps only c==0
    #pragma unroll
    for (int c = 0; c < 4; c++){
      #pragma unroll
      for (int b0h = 0; b0h < 2; b0h++){
        if (mt == 6 && c > 0) continue;
        const int r0 = 4*c + 2*b0h;
        const int P  = mt*16 + 4*c + 2*hh + b0h;
        uint4 wa = sW3E[P*2], wb = sW3E[P*2+1];
        float bA = uf(wb.z), bB = uf(wb.w);
        h2v tp0 = mkh2(fast_tanh(acc0[r0] + bA), fast_tanh(acc0[r0+1] + bB));
        h2v tp1 = mkh2(fast_tanh(acc1[r0] + bA), fast_tanh(acc1[r0+1] + bB));
        fp0[0] = dot2(uh(wa.x), tp0, fp0[0]); fp1[0] = dot2(uh(wa.x), tp1, fp1[0]);
        fp0[1] = dot2(uh(wa.y), tp0, fp0[1]); fp1[1] = dot2(uh(wa.y), tp1, fp1[1]);
        fp0[2] = dot2(uh(wa.z), tp0, fp0[2]); fp1[2] = dot2(uh(wa.z), tp1, fp1[2]);
        fp0[3] = dot2(uh(wa.w), tp0, fp0[3]); fp1[3] = dot2(uh(wa.w), tp1, fp1[3]);
        fp0[4] = dot2(uh(wb.x), tp0, fp0[4]); fp1[4] = dot2(uh(wb.x), tp1, fp1[4]);
        fp0[5] = dot2(uh(wb.y), tp0, fp0[5]); fp1[5] = dot2(uh(wb.y), tp1, fp1[5]);
      }
    }
  }
  float f[6];
  #pragma unroll
  for (int d = 0; d < 6; d++){
    float s0 = fp0[d] + __shfl_xor(fp0[d], 32, 64);
    float s1 = fp1[d] + __shfl_xor(fp1[d], 32, 64);
    f[d] = sFB3[d] + (hh ? s1 : s0);
  }

  // ============ ICNN z1 -> sp1 packed ============
  uint sp1p[32];
  #pragma unroll
  for (int p = 0; p < 30; p++){
    uint4 wA = sPI1B[2*p], wB = sPI1B[2*p+1];
    float za = uf(wA.w), zb = uf(wB.w);
    za = dot2(uh(wA.x), xp[0], za); za = dot2(uh(wA.y), xp[1], za); za = dot2(uh(wA.z), xp[2], za);
    zb = dot2(uh(wB.x), xp[0], zb); zb = dot2(uh(wB.y), xp[1], zb); zb = dot2(uh(wB.z), xp[2], zb);
    sp1p[p] = packh(fast_sp(za), fast_sp(zb));
  }
  sp1p[30] = 0u; sp1p[31] = 0u;

  // ============ z2 = W2*sp1 via MFMA (split by m-half; 256-VGPR budget) ======
  uint zbf0[4][4], zbf1[4][4];
  {
    int a0 = 4 * l31;
    int a1 = 4 * (32 + l31);
    #pragma unroll
    for (int kt = 0; kt < 4; kt++){
      #pragma unroll
      for (int q = 0; q < 4; q++){
        int lo0 = __builtin_amdgcn_ds_bpermute(a0, (int)sp1p[kt*8 + q]);
        int hi0 = __builtin_amdgcn_ds_bpermute(a0, (int)sp1p[kt*8 + 4 + q]);
        zbf0[kt][q] = hh ? (uint)hi0 : (uint)lo0;
        int lo1 = __builtin_amdgcn_ds_bpermute(a1, (int)sp1p[kt*8 + q]);
        int hi1 = __builtin_amdgcn_ds_bpermute(a1, (int)sp1p[kt*8 + 4 + q]);
        zbf1[kt][q] = hh ? (uint)hi1 : (uint)lo1;
      }
    }
  }
  uint c2p[32];
  #pragma unroll
  for (int m = 0; m < 2; m++){
    f16x8 af[4];
    #pragma unroll
    for (int kt = 0; kt < 4; kt++){
      const ushort* wp = &sA2[(m*32+l31)*68 + kt*16 + 8*hh];
      uint2 w0 = *(const uint2*)wp;
      uint2 w1 = *(const uint2*)(wp + 4);
      uint4 au; au.x = w0.x; au.y = w0.y; au.z = w1.x; au.w = w1.y;
      af[kt] = __builtin_bit_cast(f16x8, au);
    }
    f32x16 za0 = {0,0,0,0,0,0,0,0,0,0,0,0,0,0,0,0};
    f32x16 za1 = {0,0,0,0,0,0,0,0,0,0,0,0,0,0,0,0};
    #pragma unroll
    for (int kt = 0; kt < 4; kt++){
      uint4 b0u; b0u.x=zbf0[kt][0]; b0u.y=zbf0[kt][1]; b0u.z=zbf0[kt][2]; b0u.w=zbf0[kt][3];
      uint4 b1u; b1u.x=zbf1[kt][0]; b1u.y=zbf1[kt][1]; b1u.z=zbf1[kt][2]; b1u.w=zbf1[kt][3];
      za0 = __builtin_amdgcn_mfma_f32_32x32x16_f16(af[kt], __builtin_bit_cast(f16x8, b0u), za0, 0, 0, 0);
      za1 = __builtin_amdgcn_mfma_f32_32x32x16_f16(af[kt], __builtin_bit_cast(f16x8, b1u), za1, 0, 0, 0);
    }
    // exchange the partner-half rows (send opposite-nt, f16-packed)
    uint ru[8];
    #pragma unroll
    for (int rp = 0; rp < 8; rp++){
      float s0 = hh ? za0[2*rp]   : za1[2*rp];
      float s1 = hh ? za0[2*rp+1] : za1[2*rp+1];
      ru[rp] = (uint)__shfl_xor((int)packh(s0, s1), 32, 64);
    }
    // assemble this half's c2p slots: [own | partner]
    #pragma unroll
    for (int rp = 0; rp < 8; rp++){
      const int pb = 2*(rp&1) + 8*(rp>>1);
      int rowb = m*32 + pb + 4*hh;
      uint4 i0 = sPM2B[rowb], i1 = sPM2B[rowb+1];
      float zlo = uf(i0.w) + (hh ? za1[2*rp]   : za0[2*rp]);
      float zhi = uf(i1.w) + (hh ? za1[2*rp+1] : za0[2*rp+1]);
      zlo = dot2(uh(i0.x), xp[0], zlo); zlo = dot2(uh(i0.y), xp[1], zlo); zlo = dot2(uh(i0.z), xp[2], zlo);
      zhi = dot2(uh(i1.x), xp[0], zhi); zhi = dot2(uh(i1.y), xp[1], zhi); zhi = dot2(uh(i1.z), xp[2], zhi);
      c2p[m*8+rp] = packh(fast_sp(zlo), fast_sp(zhi));
      int rowb2 = m*32 + pb + 4 - 4*hh;
      uint4 j0 = sPM2B[rowb2], j1 = sPM2B[rowb2+1];
      float plo = uf(j0.w) + f16lo(ru[rp]);
      float phi = uf(j1.w) + f16hi(ru[rp]);
      plo = dot2(uh(j0.x), xp[0], plo); plo = dot2(uh(j0.y), xp[1], plo); plo = dot2(uh(j0.z), xp[2], plo);
      phi = dot2(uh(j1.x), xp[0], phi); phi = dot2(uh(j1.y), xp[1], phi); phi = dot2(uh(j1.z), xp[2], phi);
      c2p[16+m*8+rp] = packh(fast_sp(plo), fast_sp(phi));
    }
  }

  // ============ z3 fwd + y + g3 (slot-addressed weight reads) ============
  float y = sIB4;
  #pragma unroll
  for (int p = 0; p < 3; p++) y = dot2(uh(sPM4u[p]), xp[p], y);
  float ac[6];
  #pragma unroll
  for (int d = 0; d < 6; d++) ac[d] = sIM4[d];
  h2v g3p[16];
  float g3even;
  #pragma unroll
  for (int i3 = 0; i3 < 30; i3++){
    uint4 m0 = sPM3B[2*i3], m1 = sPM3B[2*i3+1];
    float z = uf(m0.w);
    z = dot2(uh(m0.x), xp[0], z); z = dot2(uh(m0.y), xp[1], z); z = dot2(uh(m0.z), xp[2], z);
    const uint* prow = (const uint*)sPI3 + i3*32;
    #pragma unroll
    for (int m = 0; m < 2; m++){
      #pragma unroll
      for (int rg = 0; rg < 4; rg++){
        const int o = m*16 + rg*4;
        uint2 vo = *(const uint2*)(prow + o + 2*hh);
        z = dot2(uh(vo.x), uh(c2p[m*8+2*rg]),   z);
        z = dot2(uh(vo.y), uh(c2p[m*8+2*rg+1]), z);
        uint2 vp = *(const uint2*)(prow + o + 2 - 2*hh);
        z = dot2(uh(vp.x), uh(c2p[16+m*8+2*rg]),   z);
        z = dot2(uh(vp.y), uh(c2p[16+m*8+2*rg+1]), z);
      }
    }
    float sp3 = fast_sp(z);
    float w4  = uf(m1.x);
    y = fmaf(w4, sp3, y);
    float gi = w4 * sig_from_sp(sp3);
    if (i3 & 1) g3p[i3>>1] = mkh2(g3even, gi); else g3even = gi;
  }
  g3p[15] = mkh2(0.f, 0.f);
  #pragma unroll
  for (int q = 0; q < 15; q++){
    uint4 a = sPM3C[2*q], b = sPM3C[2*q+1];
    ac[0] = dot2(uh(a.x), g3p[q], ac[0]);
    ac[1] = dot2(uh(a.y), g3p[q], ac[1]);
    ac[2] = dot2(uh(a.z), g3p[q], ac[2]);
    ac[3] = dot2(uh(a.w), g3p[q], ac[3]);
    ac[4] = dot2(uh(b.x), g3p[q], ac[4]);
    ac[5] = dot2(uh(b.y), g3p[q], ac[5]);
  }

  // ============ bwd g2 (slot order; runtime-row weight reads) ============
  uint g2p[32];
  #pragma unroll
  for (int s = 0; s < 32; s++){
    const int mm = (s>>3)&1, rp = s&7;
    const int pb = 2*(rp&1) + 8*(rp>>1);
    int rowb = mm*32 + pb + ((s < 16) ? 4*hh : 4-4*hh);
    const uint4* r0p = sPI3C + rowb*4;
    const uint4* r1p = r0p + 4;
    float ta = 0.0f, tb = 0.0f;
    #pragma unroll
    for (int q4 = 0; q4 < 4; q4++){
      uint4 v0 = r0p[q4], v1 = r1p[q4];
      ta = dot2(uh(v0.x), g3p[4*q4+0], ta);
      ta = dot2(uh(v0.y), g3p[4*q4+1], ta);
      ta = dot2(uh(v0.z), g3p[4*q4+2], ta);
      ta = dot2(uh(v0.w), g3p[4*q4+3], ta);
      tb = dot2(uh(v1.x), g3p[4*q4+0], tb);
      tb = dot2(uh(v1.y), g3p[4*q4+1], tb);
      tb = dot2(uh(v1.z), g3p[4*q4+2], tb);
      tb = dot2(uh(v1.w), g3p[4*q4+3], tb);
    }
    h2v sp = uh(c2p[s]);
    ta *= sig_from_sp((float)sp.x);
    tb *= sig_from_sp((float)sp.y);
    h2v tp = mkh2(ta, tb);
    g2p[s] = __builtin_bit_cast(uint, tp);
    int jp = rowb >> 1;
    uint4 a = sPM2C[jp*2], b = sPM2C[jp*2+1];
    ac[0] = dot2(uh(a.x), tp, ac[0]);
    ac[1] = dot2(uh(a.y), tp, ac[1]);
    ac[2] = dot2(uh(a.z), tp, ac[2]);
    ac[3] = dot2(uh(a.w), tp, ac[3]);
    ac[4] = dot2(uh(b.x), tp, ac[4]);
    ac[5] = dot2(uh(b.y), tp, ac[5]);
  }

  // ============ bwd g1 (z1 recomputed; slot-addressed W2^T reads) ============
  #pragma unroll
  for (int p = 0; p < 30; p++){
    uint4 wA = sPI1B[2*p], wB = sPI1B[2*p+1];
    float za = uf(wA.w), zb = uf(wB.w);
    za = dot2(uh(wA.x), xp[0], za); za = dot2(uh(wA.y), xp[1], za); za = dot2(uh(wA.z), xp[2], za);
    zb = dot2(uh(wB.x), xp[0], zb); zb = dot2(uh(wB.y), xp[1], zb); zb = dot2(uh(wB.z), xp[2], zb);
    const uint* r0 = sPI2Cu + (2*p)*32;
    const uint* r1 = r0 + 32;
    float ta = 0.0f, tb = 0.0f;
    #pragma unroll
    for (int m = 0; m < 2; m++){
      #pragma unroll
      for (int rg = 0; rg < 4; rg++){
        const int o = m*16 + rg*4;
        uint2 v0o = *(const uint2*)(r0 + o + 2*hh);
        uint2 v1o = *(const uint2*)(r1 + o + 2*hh);
        ta = dot2(uh(v0o.x), uh(g2p[m*8+2*rg]),   ta);
        ta = dot2(uh(v0o.y), uh(g2p[m*8+2*rg+1]), ta);
        tb = dot2(uh(v1o.x), uh(g2p[m*8+2*rg]),   tb);
        tb = dot2(uh(v1o.y), uh(g2p[m*8+2*rg+1]), tb);
        uint2 v0p = *(const uint2*)(r0 + o + 2 - 2*hh);
        uint2 v1p = *(const uint2*)(r1 + o + 2 - 2*hh);
        ta = dot2(uh(v0p.x), uh(g2p[16+m*8+2*rg]),   ta);
        ta = dot2(uh(v0p.y), uh(g2p[16+m*8+2*rg+1]), ta);
        tb = dot2(uh(v1p.x), uh(g2p[16+m*8+2*rg]),   tb);
        tb = dot2(uh(v1p.y), uh(g2p[16+m*8+2*rg+1]), tb);
      }
    }
    ta *= fast_sig(za); tb *= fast_sig(zb);
    h2v tp = mkh2(ta, tb);
    uint4 a = sPI1C[2*p], b = sPI1C[2*p+1];
    ac[0] = dot2(uh(a.x), tp, ac[0]);
    ac[1] = dot2(uh(a.y), tp, ac[1]);
    ac[2] = dot2(uh(a.z), tp, ac[2]);
    ac[3] = dot2(uh(a.w), tp, ac[3]);
    ac[4] = dot2(uh(b.x), tp, ac[4]);
    ac[5] = dot2(uh(b.y), tp, ac[5]);
  }

  // ============ V, dV ============
  float hdiff = y - sYREF;
  float sigma = (hdiff >= 1.0f) ? (hdiff - 0.5f) : ((hdiff > 0.0f) ? 0.5f*hdiff*hdiff : 0.0f);
  float sigp  = (hdiff >= 1.0f) ? 1.0f          : ((hdiff > 0.0f) ? hdiff             : 0.0f);
  float dx2 = 0.0f;
  float dV[6];
  #pragma unroll
  for (int d = 0; d < 6; d++){
    float dx = x[d] - sXREF[d];
    dx2 = fmaf(dx, dx, dx2);
    dV[d] = fmaf(sigp, ac[d], 2.0f*EPS*dx);
  }
  float V = sigma + EPS*dx2;

  float sc = ALPHA * V;
  #pragma unroll
  for (int d = 0; d < 6; d++) sc = fmaf(dV[d], f[d], sc);

  // ============ GNN + combine ============
  float u[6];
  #pragma unroll
  for (int m = 0; m < 6; m++) u[m] = valid ? U[(long)i*6 + m] : 0.0f;
  float am[6] = {0.f,0.f,0.f,0.f,0.f,0.f};
  float gU[6];
  #pragma unroll
  for (int d = 0; d < 6; d++){
    float acc = 0.0f;
    #pragma unroll
    for (int m = 0; m < 6; m++){
      int o = d*6 + m;
      uint4 g4 = sPGB[o];
      float g = uf(g4.w);
      g = dot2(uh(g4.x), xp[0], g); g = dot2(uh(g4.y), xp[1], g); g = dot2(uh(g4.z), xp[2], g);
      am[m] = fmaf(dV[d], g, am[m]);
      acc   = fmaf(g, u[m], acc);
    }
    gU[d] = acc;
  }
  #pragma unroll
  for (int m = 0; m < 6; m++) sc -= fabsf(am[m]);

  float n2 = 0.0f;
  #pragma unroll
  for (int d = 0; d < 6; d++) n2 = fmaf(dV[d], dV[d], n2);
  float r = fmaxf(sc, 0.0f) * rcp_f(n2);

  if (valid){
    #pragma unroll
    for (int d = 0; d < 6; d++)
      out[(long)i*6 + d] = f[d] - dV[d]*r + gU[d];
  }
}

extern "C" void kernel_launch(void* const* d_in, const int* in_sizes, int n_in,
                              void* d_out, int out_size, void* d_ws, size_t ws_size,
                              hipStream_t stream)
{
  const float* X    = (const float*)d_in[0];
  const float* U    = (const float*)d_in[1];
  const float* xref = (const float*)d_in[2];
  const float* fw1  = (const float*)d_in[3];
  const float* fb1  = (const float*)d_in[4];
  const float* fw2  = (const float*)d_in[5];
  const float* fb2  = (const float*)d_in[6];
  const float* fw3  = (const float*)d_in[7];
  const float* fb3  = (const float*)d_in[8];
  const float* gw   = (const float*)d_in[9];
  const float* gb   = (const float*)d_in[10];
  const float* iw1  = (const float*)d_in[11];
  const float* ib1  = (const float*)d_in[12];
  const float* iw2  = (const float*)d_in[13];
  const float* ib2  = (const float*)d_in[14];
  const float* iw3  = (const float*)d_in[15];
  const float* ib3  = (const float*)d_in[16];
  const float* iw4  = (const float*)d_in[17];
  const float* ib4  = (const float*)d_in[18];
  const float* im2  = (const float*)d_in[19];
  const float* im3  = (const float*)d_in[20];
  const float* im4  = (const float*)d_in[21];

  float* out = (float*)d_out;
  int N = in_sizes[0] / 6;

  int threads = 512;
  int blocks  = (N + threads - 1) / threads;
  holo_main<<<blocks, threads, 0, stream>>>(X, U, xref,
      fw1, fb1, fw2, fb2, fw3, fb3, gw, gb,
      iw1, ib1, iw2, ib2, iw3, ib3, iw4, ib4, im2, im3, im4,
      out, N);
}

// Round 11
// 1922.738 us; speedup vs baseline: 1.0011x; 1.0011x over previous
//
#include <hip/hip_runtime.h>

#define EPS 1e-05f
#define ALPHA 0.05f

typedef _Float16 h2v __attribute__((ext_vector_type(2)));
typedef _Float16 f16x8 __attribute__((ext_vector_type(8)));
typedef float f32x16 __attribute__((ext_vector_type(16)));

__device__ __forceinline__ float rcp_f(float x){ return __builtin_amdgcn_rcpf(x); }
__device__ __forceinline__ float dot2(h2v a, h2v b, float c){
  return __builtin_amdgcn_fdot2(a, b, c, false);
}
__device__ __forceinline__ h2v uh(uint u){ return __builtin_bit_cast(h2v, u); }
__device__ __forceinline__ float uf(uint u){ return __builtin_bit_cast(float, u); }

#define LOG2E 1.4426950408889634f
#define LN2   0.6931471805599453f

__device__ __forceinline__ float fast_tanh(float x){
  float ax = fabsf(x);
  float e  = exp2f(ax * (-2.0f * LOG2E));
  float t  = (1.0f - e) * rcp_f(1.0f + e);
  return copysignf(t, x);
}
__device__ __forceinline__ float fast_sp(float x){
  float ax = fabsf(x);
  float e  = exp2f(ax * -LOG2E);
  return fmaxf(x, 0.0f) + log2f(1.0f + e) * LN2;
}
__device__ __forceinline__ float fast_sig(float x){
  float ax = fabsf(x);
  float e  = exp2f(ax * -LOG2E);
  float r  = rcp_f(1.0f + e);
  return x >= 0.0f ? r : e * r;
}
__device__ __forceinline__ float sig_from_sp(float sp){
  return 1.0f - exp2f(sp * -LOG2E);
}
__device__ __forceinline__ h2v mkh2(float a, float b){
  h2v r; r.x = (_Float16)a; r.y = (_Float16)b; return r;
}
__device__ __forceinline__ uint packh(float a, float b){
  ushort lo = __builtin_bit_cast(ushort, (_Float16)a);
  ushort hi = __builtin_bit_cast(ushort, (_Float16)b);
  return (uint)lo | ((uint)hi << 16);
}
__device__ __forceinline__ float f16lo(uint u){
  return (float)__builtin_bit_cast(_Float16, (ushort)(u & 0xffffu));
}
__device__ __forceinline__ float f16hi(uint u){
  return (float)__builtin_bit_cast(_Float16, (ushort)(u >> 16));
}

// ================= fused kernel: stage + pack + yref + compute =================
// amdgpu_waves_per_eu(1,2): cap assumed occupancy at 2 waves/SIMD so the
// register allocator gets a 256-VGPR budget. Plain __launch_bounds__(512,1)
// did NOT do this (R10): the backend targets LDS-implied occupancy (73.7KB ->
// 2 blocks/CU -> 4 waves/SIMD -> 128-VGPR cap) and spilled 3.66 GB/dispatch.
// R8/R10 ran at ~8 waves/CU anyway (scratch-throttled), so this trades no
// real occupancy.
__global__ __launch_bounds__(512) __attribute__((amdgpu_waves_per_eu(1, 2)))
void holo_main(
    const float* __restrict__ X, const float* __restrict__ U,
    const float* __restrict__ xref,
    const float* __restrict__ fw1, const float* __restrict__ fb1,
    const float* __restrict__ fw2, const float* __restrict__ fb2,
    const float* __restrict__ fw3, const float* __restrict__ fb3,
    const float* __restrict__ gw,  const float* __restrict__ gb,
    const float* __restrict__ iw1, const float* __restrict__ ib1,
    const float* __restrict__ iw2, const float* __restrict__ ib2,
    const float* __restrict__ iw3, const float* __restrict__ ib3,
    const float* __restrict__ iw4, const float* __restrict__ ib4,
    const float* __restrict__ im2, const float* __restrict__ im3,
    const float* __restrict__ im4,
    float* __restrict__ out, int N)
{
  // ---- LDS (natural layouts, zero-padded; reads use runtime hh offsets) ----
  __shared__ alignas(16) ushort sW2r[224*84]; // fw2 MFMA-A [224 rows][84 halves]
  __shared__ uint4 sW3E[224];   // 112 n-pairs x2: {w3 d0..d5 pairs, fb2[n], fb2[n+1]}
  __shared__ alignas(16) ushort sA2[64*68];   // iw2 MFMA-A [64 rows j][68 halves k]
  __shared__ uint4 sPW1B[80];   // fw1 row o: {w01,w23,w45, fb1[o]}
  __shared__ uint4 sPGB[36];    // gw  row o: {w01,w23,w45, gb[o]}
  __shared__ uint4 sPI1B[60];   // iw1 rows: {w,b} pairs
  __shared__ uint4 sPI1C[60];   // iw1^T pairs [30 kp][6 d + pad]
  __shared__ uint4 sPI3[240];   // iw3 [30 i3][32 jp] (jp 30,31 = 0)
  __shared__ uint4 sPI3C[256];  // iw3^T [64 j][16 qp] (rows 60-63, qp 15 = 0)
  __shared__ uint4 sPM2B[64];   // im2 row j: {w01,w23,w45, ib2[j]} (rows 60-63 = 0)
  __shared__ uint4 sPM2C[64];   // im2^T [32 jp][8] (jp 30,31 = 0)
  __shared__ uint4 sPM3B[60];   // im3 rows: {w,ib3 | iw4,0,0,0}
  __shared__ uint4 sPM3C[30];   // im3^T [15 qp][8]
  __shared__ uint  sPM4u[4];    // im4 pairs
  __shared__ alignas(16) uint sPI2Cu[60*32]; // iw2^T [60 k1][32 jp] (jp 30,31 = 0)
  __shared__ float sFB3[6], sXREF[6], sIM4[6];
  __shared__ float sS1[60], sS2[60], sS3[30];
  __shared__ float sYREF, sIB4;

  const int t = threadIdx.x;
  const int T = 512;
  const int lane = t & 63;
  const int hh  = lane >> 5;
  const int l31 = lane & 31;

  // ---- stage + pack from original weights ----
  for (int idx=t; idx<224*42; idx+=T){
    int row = idx/42, c = idx%42, k = 2*c;
    uint v = 0;
    if (row < 200 && k < 80) v = packh(fw2[row*80+k], fw2[row*80+k+1]);
    ((uint*)sW2r)[idx] = v;
  }
  for (int idx=t; idx<896; idx+=T){
    int P = idx/8, c = idx%8, n = 2*P;
    uint v = 0;
    if (n < 200){
      if (c < 6)       v = packh(fw3[c*200+n], fw3[c*200+n+1]);
      else if (c == 6) v = __builtin_bit_cast(uint, fb2[n]);
      else             v = __builtin_bit_cast(uint, fb2[n+1]);
    }
    ((uint*)sW3E)[idx] = v;
  }
  for (int idx=t; idx<64*34; idx+=T){           // sA2
    int row = idx/34, c = idx%34, k = 2*c;
    uint v = 0;
    if (row < 60 && c < 30) v = packh(iw2[row*60+k], iw2[row*60+k+1]);
    ((uint*)sA2)[idx] = v;
  }
  for (int idx=t; idx<320; idx+=T){
    int o = idx/4, c = idx%4;
    ((uint*)sPW1B)[idx] = (c<3) ? packh(fw1[o*6+2*c], fw1[o*6+2*c+1])
                                : __builtin_bit_cast(uint, fb1[o]);
  }
  for (int idx=t; idx<144; idx+=T){
    int o = idx/4, c = idx%4;
    ((uint*)sPGB)[idx] = (c<3) ? packh(gw[o*6+2*c], gw[o*6+2*c+1])
                               : __builtin_bit_cast(uint, gb[o]);
  }
  for (int idx=t; idx<240; idx+=T){
    int p = idx/8, c = idx%8, sub = c/4, cc = c%4, nr = 2*p+sub;
    ((uint*)sPI1B)[idx] = (cc<3) ? packh(iw1[nr*6+2*cc], iw1[nr*6+2*cc+1])
                                 : __builtin_bit_cast(uint, ib1[nr]);
  }
  for (int idx=t; idx<240; idx+=T){
    int q = idx/8, c = idx%8;
    ((uint*)sPI1C)[idx] = (c<6) ? packh(iw1[(2*q)*6+c], iw1[(2*q+1)*6+c]) : 0u;
  }
  for (int idx=t; idx<960; idx+=T){
    int r = idx/32, q = idx%32;
    ((uint*)sPI3)[idx] = (q<30) ? packh(iw3[r*60+2*q], iw3[r*60+2*q+1]) : 0u;
  }
  for (int idx=t; idx<1024; idx+=T){
    int j = idx/16, q = idx%16;
    ((uint*)sPI3C)[idx] = (j<60 && q<15) ? packh(iw3[(2*q)*60+j], iw3[(2*q+1)*60+j]) : 0u;
  }
  for (int idx=t; idx<256; idx+=T){
    int j = idx/4, c = idx%4;
    uint v = 0;
    if (j < 60) v = (c<3) ? packh(im2[j*6+2*c], im2[j*6+2*c+1])
                          : __builtin_bit_cast(uint, ib2[j]);
    ((uint*)sPM2B)[idx] = v;
  }
  for (int idx=t; idx<256; idx+=T){
    int q = idx/8, c = idx%8;
    ((uint*)sPM2C)[idx] = (q<30 && c<6) ? packh(im2[(2*q)*6+c], im2[(2*q+1)*6+c]) : 0u;
  }
  for (int idx=t; idx<240; idx+=T){
    int r = idx/8, c = idx%8;
    uint v = 0;
    if (c < 3)       v = packh(im3[r*6+2*c], im3[r*6+2*c+1]);
    else if (c == 3) v = __builtin_bit_cast(uint, ib3[r]);
    else if (c == 4) v = __builtin_bit_cast(uint, iw4[r]);
    ((uint*)sPM3B)[idx] = v;
  }
  for (int idx=t; idx<120; idx+=T){
    int q = idx/8, c = idx%8;
    ((uint*)sPM3C)[idx] = (c<6) ? packh(im3[(2*q)*6+c], im3[(2*q+1)*6+c]) : 0u;
  }
  for (int idx=t; idx<4; idx+=T)
    sPM4u[idx] = (idx<3) ? packh(im4[2*idx], im4[2*idx+1]) : 0u;
  for (int idx=t; idx<1920; idx+=T){
    int k1 = idx/32, q = idx%32;
    sPI2Cu[idx] = (q<30) ? packh(iw2[(2*q)*60+k1], iw2[(2*q+1)*60+k1]) : 0u;
  }
  for (int k=t;k<6;k+=T){ sFB3[k]=fb3[k]; sIM4[k]=im4[k]; sXREF[k]=xref[k]; }
  if (t==0) sIB4=ib4[0];
  __syncthreads();

  // ---- cooperative yref = icnn(xref) from the SAME packed f16 weights ----
  {
    h2v xrp[3];
    #pragma unroll
    for (int p = 0; p < 3; p++) xrp[p] = mkh2(sXREF[2*p], sXREF[2*p+1]);
    if (t < 60){
      const uint* w = (const uint*)sPI1B + (t/2)*8 + (t&1)*4;
      float z = uf(w[3]);
      #pragma unroll
      for (int c = 0; c < 3; c++) z = dot2(uh(w[c]), xrp[c], z);
      sS1[t] = fast_sp(z);
    }
    __syncthreads();
    if (t < 60){
      const uint* m = (const uint*)sPM2B + t*4;
      float z = uf(m[3]);
      #pragma unroll
      for (int c = 0; c < 3; c++) z = dot2(uh(m[c]), xrp[c], z);
      const uint* arow = (const uint*)sA2 + t*34;
      for (int q = 0; q < 30; q++)
        z = dot2(uh(arow[q]), mkh2(sS1[2*q], sS1[2*q+1]), z);
      sS2[t] = fast_sp(z);
    }
    __syncthreads();
    if (t < 30){
      const uint* m = (const uint*)sPM3B + t*8;
      float z = uf(m[3]);
      #pragma unroll
      for (int c = 0; c < 3; c++) z = dot2(uh(m[c]), xrp[c], z);
      const uint* prow = (const uint*)sPI3 + t*32;
      for (int q = 0; q < 30; q++)
        z = dot2(uh(prow[q]), mkh2(sS2[2*q], sS2[2*q+1]), z);
      sS3[t] = fast_sp(z);
    }
    __syncthreads();
    if (t == 0){
      float y = sIB4;
      #pragma unroll
      for (int p = 0; p < 3; p++) y = dot2(uh(sPM4u[p]), xrp[p], y);
      for (int j = 0; j < 30; j++) y = fmaf(uf(((const uint*)sPM3B)[j*8+4]), sS3[j], y);
      sYREF = y;
    }
    __syncthreads();
  }

  // ---- per-thread sample compute (guarded loads/stores, full-wave execution) ----
  const int i = blockIdx.x * blockDim.x + t;
  const bool valid = (i < N);

  float x[6]; h2v xp[3];
  #pragma unroll
  for (int k = 0; k < 6; k++) x[k] = valid ? X[(long)i*6 + k] : 0.0f;
  #pragma unroll
  for (int p = 0; p < 3; p++) xp[p] = mkh2(x[2*p], x[2*p+1]);

  // ============ FNN layer 1: 6 -> 80, tanh ============
  uint h1u[40];
  #pragma unroll
  for (int o = 0; o < 80; o += 2){
    uint4 wa = sPW1B[o], wb = sPW1B[o+1];
    float z0 = uf(wa.w), z1 = uf(wb.w);
    z0 = dot2(uh(wa.x), xp[0], z0); z0 = dot2(uh(wa.y), xp[1], z0); z0 = dot2(uh(wa.z), xp[2], z0);
    z1 = dot2(uh(wb.x), xp[0], z1); z1 = dot2(uh(wb.y), xp[1], z1); z1 = dot2(uh(wb.z), xp[2], z1);
    h1u[o/2] = packh(fast_tanh(z0), fast_tanh(z1));
  }

  // ============ FNN L2+L3 via MFMA (32x32x16 f16) ============
  uint bf0[5][4], bf1[5][4];
  {
    int a0 = 4 * l31;
    int a1 = 4 * (32 + l31);
    #pragma unroll
    for (int kt = 0; kt < 5; kt++){
      #pragma unroll
      for (int q = 0; q < 4; q++){
        int lo0 = __builtin_amdgcn_ds_bpermute(a0, (int)h1u[kt*8 + q]);
        int hi0 = __builtin_amdgcn_ds_bpermute(a0, (int)h1u[kt*8 + 4 + q]);
        bf0[kt][q] = hh ? (uint)hi0 : (uint)lo0;
        int lo1 = __builtin_amdgcn_ds_bpermute(a1, (int)h1u[kt*8 + q]);
        int hi1 = __builtin_amdgcn_ds_bpermute(a1, (int)h1u[kt*8 + 4 + q]);
        bf1[kt][q] = hh ? (uint)hi1 : (uint)lo1;
      }
    }
  }

  float fp0[6] = {0.f,0.f,0.f,0.f,0.f,0.f};
  float fp1[6] = {0.f,0.f,0.f,0.f,0.f,0.f};
  for (int mt = 0; mt < 7; mt++){
    const int row = mt*32 + l31;
    f16x8 af[5];
    #pragma unroll
    for (int kt = 0; kt < 5; kt++){
      const ushort* wp = &sW2r[row*84 + kt*16 + 8*hh];
      uint2 w0 = *(const uint2*)wp;
      uint2 w1 = *(const uint2*)(wp + 4);
      uint4 au; au.x = w0.x; au.y = w0.y; au.z = w1.x; au.w = w1.y;
      af[kt] = __builtin_bit_cast(f16x8, au);
    }
    f32x16 acc0 = {0,0,0,0,0,0,0,0,0,0,0,0,0,0,0,0};
    f32x16 acc1 = {0,0,0,0,0,0,0,0,0,0,0,0,0,0,0,0};
    #pragma unroll
    for (int kt = 0; kt < 5; kt++){
      uint4 b0u; b0u.x=bf0[kt][0]; b0u.y=bf0[kt][1]; b0u.z=bf0[kt][2]; b0u.w=bf0[kt][3];
      uint4 b1u; b1u.x=bf1[kt][0]; b1u.y=bf1[kt][1]; b1u.z=bf1[kt][2]; b1u.w=bf1[kt][3];
      acc0 = __builtin_amdgcn_mfma_f32_32x32x16_f16(af[kt], __builtin_bit_cast(f16x8, b0u), acc0, 0, 0, 0);
      acc1 = __builtin_amdgcn_mfma_f32_32x32x16_f16(af[kt], __builtin_bit_cast(f16x8, b1u), acc1, 0, 0, 0);
    }
    // epilogue (neuron pairs); rows 200-223 are zero-pad -> mt==6 keeps only c==0
    #pragma unroll
    for (int c = 0; c < 4; c++){
      #pragma unroll
      for (int b0h = 0; b0h < 2; b0h++){
        if (mt == 6 && c > 0) continue;
        const int r0 = 4*c + 2*b0h;
        const int P  = mt*16 + 4*c + 2*hh + b0h;
        uint4 wa = sW3E[P*2], wb = sW3E[P*2+1];
        float bA = uf(wb.z), bB = uf(wb.w);
        h2v tp0 = mkh2(fast_tanh(acc0[r0] + bA), fast_tanh(acc0[r0+1] + bB));
        h2v tp1 = mkh2(fast_tanh(acc1[r0] + bA), fast_tanh(acc1[r0+1] + bB));
        fp0[0] = dot2(uh(wa.x), tp0, fp0[0]); fp1[0] = dot2(uh(wa.x), tp1, fp1[0]);
        fp0[1] = dot2(uh(wa.y), tp0, fp0[1]); fp1[1] = dot2(uh(wa.y), tp1, fp1[1]);
        fp0[2] = dot2(uh(wa.z), tp0, fp0[2]); fp1[2] = dot2(uh(wa.z), tp1, fp1[2]);
        fp0[3] = dot2(uh(wa.w), tp0, fp0[3]); fp1[3] = dot2(uh(wa.w), tp1, fp1[3]);
        fp0[4] = dot2(uh(wb.x), tp0, fp0[4]); fp1[4] = dot2(uh(wb.x), tp1, fp1[4]);
        fp0[5] = dot2(uh(wb.y), tp0, fp0[5]); fp1[5] = dot2(uh(wb.y), tp1, fp1[5]);
      }
    }
  }
  float f[6];
  #pragma unroll
  for (int d = 0; d < 6; d++){
    float s0 = fp0[d] + __shfl_xor(fp0[d], 32, 64);
    float s1 = fp1[d] + __shfl_xor(fp1[d], 32, 64);
    f[d] = sFB3[d] + (hh ? s1 : s0);
  }

  // ============ ICNN z1 -> sp1 packed ============
  uint sp1p[32];
  #pragma unroll
  for (int p = 0; p < 30; p++){
    uint4 wA = sPI1B[2*p], wB = sPI1B[2*p+1];
    float za = uf(wA.w), zb = uf(wB.w);
    za = dot2(uh(wA.x), xp[0], za); za = dot2(uh(wA.y), xp[1], za); za = dot2(uh(wA.z), xp[2], za);
    zb = dot2(uh(wB.x), xp[0], zb); zb = dot2(uh(wB.y), xp[1], zb); zb = dot2(uh(wB.z), xp[2], zb);
    sp1p[p] = packh(fast_sp(za), fast_sp(zb));
  }
  sp1p[30] = 0u; sp1p[31] = 0u;

  // ============ z2 = W2*sp1 via MFMA (split by m-half; 256-VGPR budget) ======
  uint zbf0[4][4], zbf1[4][4];
  {
    int a0 = 4 * l31;
    int a1 = 4 * (32 + l31);
    #pragma unroll
    for (int kt = 0; kt < 4; kt++){
      #pragma unroll
      for (int q = 0; q < 4; q++){
        int lo0 = __builtin_amdgcn_ds_bpermute(a0, (int)sp1p[kt*8 + q]);
        int hi0 = __builtin_amdgcn_ds_bpermute(a0, (int)sp1p[kt*8 + 4 + q]);
        zbf0[kt][q] = hh ? (uint)hi0 : (uint)lo0;
        int lo1 = __builtin_amdgcn_ds_bpermute(a1, (int)sp1p[kt*8 + q]);
        int hi1 = __builtin_amdgcn_ds_bpermute(a1, (int)sp1p[kt*8 + 4 + q]);
        zbf1[kt][q] = hh ? (uint)hi1 : (uint)lo1;
      }
    }
  }
  uint c2p[32];
  #pragma unroll
  for (int m = 0; m < 2; m++){
    f16x8 af[4];
    #pragma unroll
    for (int kt = 0; kt < 4; kt++){
      const ushort* wp = &sA2[(m*32+l31)*68 + kt*16 + 8*hh];
      uint2 w0 = *(const uint2*)wp;
      uint2 w1 = *(const uint2*)(wp + 4);
      uint4 au; au.x = w0.x; au.y = w0.y; au.z = w1.x; au.w = w1.y;
      af[kt] = __builtin_bit_cast(f16x8, au);
    }
    f32x16 za0 = {0,0,0,0,0,0,0,0,0,0,0,0,0,0,0,0};
    f32x16 za1 = {0,0,0,0,0,0,0,0,0,0,0,0,0,0,0,0};
    #pragma unroll
    for (int kt = 0; kt < 4; kt++){
      uint4 b0u; b0u.x=zbf0[kt][0]; b0u.y=zbf0[kt][1]; b0u.z=zbf0[kt][2]; b0u.w=zbf0[kt][3];
      uint4 b1u; b1u.x=zbf1[kt][0]; b1u.y=zbf1[kt][1]; b1u.z=zbf1[kt][2]; b1u.w=zbf1[kt][3];
      za0 = __builtin_amdgcn_mfma_f32_32x32x16_f16(af[kt], __builtin_bit_cast(f16x8, b0u), za0, 0, 0, 0);
      za1 = __builtin_amdgcn_mfma_f32_32x32x16_f16(af[kt], __builtin_bit_cast(f16x8, b1u), za1, 0, 0, 0);
    }
    // exchange the partner-half rows (send opposite-nt, f16-packed)
    uint ru[8];
    #pragma unroll
    for (int rp = 0; rp < 8; rp++){
      float s0 = hh ? za0[2*rp]   : za1[2*rp];
      float s1 = hh ? za0[2*rp+1] : za1[2*rp+1];
      ru[rp] = (uint)__shfl_xor((int)packh(s0, s1), 32, 64);
    }
    // assemble this half's c2p slots: [own | partner]
    #pragma unroll
    for (int rp = 0; rp < 8; rp++){
      const int pb = 2*(rp&1) + 8*(rp>>1);
      int rowb = m*32 + pb + 4*hh;
      uint4 i0 = sPM2B[rowb], i1 = sPM2B[rowb+1];
      float zlo = uf(i0.w) + (hh ? za1[2*rp]   : za0[2*rp]);
      float zhi = uf(i1.w) + (hh ? za1[2*rp+1] : za0[2*rp+1]);
      zlo = dot2(uh(i0.x), xp[0], zlo); zlo = dot2(uh(i0.y), xp[1], zlo); zlo = dot2(uh(i0.z), xp[2], zlo);
      zhi = dot2(uh(i1.x), xp[0], zhi); zhi = dot2(uh(i1.y), xp[1], zhi); zhi = dot2(uh(i1.z), xp[2], zhi);
      c2p[m*8+rp] = packh(fast_sp(zlo), fast_sp(zhi));
      int rowb2 = m*32 + pb + 4 - 4*hh;
      uint4 j0 = sPM2B[rowb2], j1 = sPM2B[rowb2+1];
      float plo = uf(j0.w) + f16lo(ru[rp]);
      float phi = uf(j1.w) + f16hi(ru[rp]);
      plo = dot2(uh(j0.x), xp[0], plo); plo = dot2(uh(j0.y), xp[1], plo); plo = dot2(uh(j0.z), xp[2], plo);
      phi = dot2(uh(j1.x), xp[0], phi); phi = dot2(uh(j1.y), xp[1], phi); phi = dot2(uh(j1.z), xp[2], phi);
      c2p[16+m*8+rp] = packh(fast_sp(plo), fast_sp(phi));
    }
  }

  // ============ z3 fwd + y + g3 (slot-addressed weight reads) ============
  float y = sIB4;
  #pragma unroll
  for (int p = 0; p < 3; p++) y = dot2(uh(sPM4u[p]), xp[p], y);
  float ac[6];
  #pragma unroll
  for (int d = 0; d < 6; d++) ac[d] = sIM4[d];
  h2v g3p[16];
  float g3even;
  #pragma unroll
  for (int i3 = 0; i3 < 30; i3++){
    uint4 m0 = sPM3B[2*i3], m1 = sPM3B[2*i3+1];
    float z = uf(m0.w);
    z = dot2(uh(m0.x), xp[0], z); z = dot2(uh(m0.y), xp[1], z); z = dot2(uh(m0.z), xp[2], z);
    const uint* prow = (const uint*)sPI3 + i3*32;
    #pragma unroll
    for (int m = 0; m < 2; m++){
      #pragma unroll
      for (int rg = 0; rg < 4; rg++){
        const int o = m*16 + rg*4;
        uint2 vo = *(const uint2*)(prow + o + 2*hh);
        z = dot2(uh(vo.x), uh(c2p[m*8+2*rg]),   z);
        z = dot2(uh(vo.y), uh(c2p[m*8+2*rg+1]), z);
        uint2 vp = *(const uint2*)(prow + o + 2 - 2*hh);
        z = dot2(uh(vp.x), uh(c2p[16+m*8+2*rg]),   z);
        z = dot2(uh(vp.y), uh(c2p[16+m*8+2*rg+1]), z);
      }
    }
    float sp3 = fast_sp(z);
    float w4  = uf(m1.x);
    y = fmaf(w4, sp3, y);
    float gi = w4 * sig_from_sp(sp3);
    if (i3 & 1) g3p[i3>>1] = mkh2(g3even, gi); else g3even = gi;
  }
  g3p[15] = mkh2(0.f, 0.f);
  #pragma unroll
  for (int q = 0; q < 15; q++){
    uint4 a = sPM3C[2*q], b = sPM3C[2*q+1];
    ac[0] = dot2(uh(a.x), g3p[q], ac[0]);
    ac[1] = dot2(uh(a.y), g3p[q], ac[1]);
    ac[2] = dot2(uh(a.z), g3p[q], ac[2]);
    ac[3] = dot2(uh(a.w), g3p[q], ac[3]);
    ac[4] = dot2(uh(b.x), g3p[q], ac[4]);
    ac[5] = dot2(uh(b.y), g3p[q], ac[5]);
  }

  // ============ bwd g2 (slot order; runtime-row weight reads) ============
  uint g2p[32];
  #pragma unroll
  for (int s = 0; s < 32; s++){
    const int mm = (s>>3)&1, rp = s&7;
    const int pb = 2*(rp&1) + 8*(rp>>1);
    int rowb = mm*32 + pb + ((s < 16) ? 4*hh : 4-4*hh);
    const uint4* r0p = sPI3C + rowb*4;
    const uint4* r1p = r0p + 4;
    float ta = 0.0f, tb = 0.0f;
    #pragma unroll
    for (int q4 = 0; q4 < 4; q4++){
      uint4 v0 = r0p[q4], v1 = r1p[q4];
      ta = dot2(uh(v0.x), g3p[4*q4+0], ta);
      ta = dot2(uh(v0.y), g3p[4*q4+1], ta);
      ta = dot2(uh(v0.z), g3p[4*q4+2], ta);
      ta = dot2(uh(v0.w), g3p[4*q4+3], ta);
      tb = dot2(uh(v1.x), g3p[4*q4+0], tb);
      tb = dot2(uh(v1.y), g3p[4*q4+1], tb);
      tb = dot2(uh(v1.z), g3p[4*q4+2], tb);
      tb = dot2(uh(v1.w), g3p[4*q4+3], tb);
    }
    h2v sp = uh(c2p[s]);
    ta *= sig_from_sp((float)sp.x);
    tb *= sig_from_sp((float)sp.y);
    h2v tp = mkh2(ta, tb);
    g2p[s] = __builtin_bit_cast(uint, tp);
    int jp = rowb >> 1;
    uint4 a = sPM2C[jp*2], b = sPM2C[jp*2+1];
    ac[0] = dot2(uh(a.x), tp, ac[0]);
    ac[1] = dot2(uh(a.y), tp, ac[1]);
    ac[2] = dot2(uh(a.z), tp, ac[2]);
    ac[3] = dot2(uh(a.w), tp, ac[3]);
    ac[4] = dot2(uh(b.x), tp, ac[4]);
    ac[5] = dot2(uh(b.y), tp, ac[5]);
  }

  // ============ bwd g1 (z1 recomputed; slot-addressed W2^T reads) ============
  #pragma unroll
  for (int p = 0; p < 30; p++){
    uint4 wA = sPI1B[2*p], wB = sPI1B[2*p+1];
    float za = uf(wA.w), zb = uf(wB.w);
    za = dot2(uh(wA.x), xp[0], za); za = dot2(uh(wA.y), xp[1], za); za = dot2(uh(wA.z), xp[2], za);
    zb = dot2(uh(wB.x), xp[0], zb); zb = dot2(uh(wB.y), xp[1], zb); zb = dot2(uh(wB.z), xp[2], zb);
    const uint* r0 = sPI2Cu + (2*p)*32;
    const uint* r1 = r0 + 32;
    float ta = 0.0f, tb = 0.0f;
    #pragma unroll
    for (int m = 0; m < 2; m++){
      #pragma unroll
      for (int rg = 0; rg < 4; rg++){
        const int o = m*16 + rg*4;
        uint2 v0o = *(const uint2*)(r0 + o + 2*hh);
        uint2 v1o = *(const uint2*)(r1 + o + 2*hh);
        ta = dot2(uh(v0o.x), uh(g2p[m*8+2*rg]),   ta);
        ta = dot2(uh(v0o.y), uh(g2p[m*8+2*rg+1]), ta);
        tb = dot2(uh(v1o.x), uh(g2p[m*8+2*rg]),   tb);
        tb = dot2(uh(v1o.y), uh(g2p[m*8+2*rg+1]), tb);
        uint2 v0p = *(const uint2*)(r0 + o + 2 - 2*hh);
        uint2 v1p = *(const uint2*)(r1 + o + 2 - 2*hh);
        ta = dot2(uh(v0p.x), uh(g2p[16+m*8+2*rg]),   ta);
        ta = dot2(uh(v0p.y), uh(g2p[16+m*8+2*rg+1]), ta);
        tb = dot2(uh(v1p.x), uh(g2p[16+m*8+2*rg]),   tb);
        tb = dot2(uh(v1p.y), uh(g2p[16+m*8+2*rg+1]), tb);
      }
    }
    ta *= fast_sig(za); tb *= fast_sig(zb);
    h2v tp = mkh2(ta, tb);
    uint4 a = sPI1C[2*p], b = sPI1C[2*p+1];
    ac[0] = dot2(uh(a.x), tp, ac[0]);
    ac[1] = dot2(uh(a.y), tp, ac[1]);
    ac[2] = dot2(uh(a.z), tp, ac[2]);
    ac[3] = dot2(uh(a.w), tp, ac[3]);
    ac[4] = dot2(uh(b.x), tp, ac[4]);
    ac[5] = dot2(uh(b.y), tp, ac[5]);
  }

  // ============ V, dV ============
  float hdiff = y - sYREF;
  float sigma = (hdiff >= 1.0f) ? (hdiff - 0.5f) : ((hdiff > 0.0f) ? 0.5f*hdiff*hdiff : 0.0f);
  float sigp  = (hdiff >= 1.0f) ? 1.0f          : ((hdiff > 0.0f) ? hdiff             : 0.0f);
  float dx2 = 0.0f;
  float dV[6];
  #pragma unroll
  for (int d = 0; d < 6; d++){
    float dx = x[d] - sXREF[d];
    dx2 = fmaf(dx, dx, dx2);
    dV[d] = fmaf(sigp, ac[d], 2.0f*EPS*dx);
  }
  float V = sigma + EPS*dx2;

  float sc = ALPHA * V;
  #pragma unroll
  for (int d = 0; d < 6; d++) sc = fmaf(dV[d], f[d], sc);

  // ============ GNN + combine ============
  float u[6];
  #pragma unroll
  for (int m = 0; m < 6; m++) u[m] = valid ? U[(long)i*6 + m] : 0.0f;
  float am[6] = {0.f,0.f,0.f,0.f,0.f,0.f};
  float gU[6];
  #pragma unroll
  for (int d = 0; d < 6; d++){
    float acc = 0.0f;
    #pragma unroll
    for (int m = 0; m < 6; m++){
      int o = d*6 + m;
      uint4 g4 = sPGB[o];
      float g = uf(g4.w);
      g = dot2(uh(g4.x), xp[0], g); g = dot2(uh(g4.y), xp[1], g); g = dot2(uh(g4.z), xp[2], g);
      am[m] = fmaf(dV[d], g, am[m]);
      acc   = fmaf(g, u[m], acc);
    }
    gU[d] = acc;
  }
  #pragma unroll
  for (int m = 0; m < 6; m++) sc -= fabsf(am[m]);

  float n2 = 0.0f;
  #pragma unroll
  for (int d = 0; d < 6; d++) n2 = fmaf(dV[d], dV[d], n2);
  float r = fmaxf(sc, 0.0f) * rcp_f(n2);

  if (valid){
    #pragma unroll
    for (int d = 0; d < 6; d++)
      out[(long)i*6 + d] = f[d] - dV[d]*r + gU[d];
  }
}

extern "C" void kernel_launch(void* const* d_in, const int* in_sizes, int n_in,
                              void* d_out, int out_size, void* d_ws, size_t ws_size,
                              hipStream_t stream)
{
  const float* X    = (const float*)d_in[0];
  const float* U    = (const float*)d_in[1];
  const float* xref = (const float*)d_in[2];
  const float* fw1  = (const float*)d_in[3];
  const float* fb1  = (const float*)d_in[4];
  const float* fw2  = (const float*)d_in[5];
  const float* fb2  = (const float*)d_in[6];
  const float* fw3  = (const float*)d_in[7];
  const float* fb3  = (const float*)d_in[8];
  const float* gw   = (const float*)d_in[9];
  const float* gb   = (const float*)d_in[10];
  const float* iw1  = (const float*)d_in[11];
  const float* ib1  = (const float*)d_in[12];
  const float* iw2  = (const float*)d_in[13];
  const float* ib2  = (const float*)d_in[14];
  const float* iw3  = (const float*)d_in[15];
  const float* ib3  = (const float*)d_in[16];
  const float* iw4  = (const float*)d_in[17];
  const float* ib4  = (const float*)d_in[18];
  const float* im2  = (const float*)d_in[19];
  const float* im3  = (const float*)d_in[20];
  const float* im4  = (const float*)d_in[21];

  float* out = (float*)d_out;
  int N = in_sizes[0] / 6;

  int threads = 512;
  int blocks  = (N + threads - 1) / threads;
  holo_main<<<blocks, threads, 0, stream>>>(X, U, xref,
      fw1, fb1, fw2, fb2, fw3, fb3, gw, gb,
      iw1, ib1, iw2, ib2, iw3, ib3, iw4, ib4, im2, im3, im4,
      out, N);
}

// Round 12
// 179.177 us; speedup vs baseline: 10.7430x; 10.7309x over previous
//
#include <hip/hip_runtime.h>

#define EPS 1e-05f
#define ALPHA 0.05f

typedef _Float16 h2v __attribute__((ext_vector_type(2)));
typedef _Float16 f16x8 __attribute__((ext_vector_type(8)));
typedef float f32x16 __attribute__((ext_vector_type(16)));

__device__ __forceinline__ float rcp_f(float x){ return __builtin_amdgcn_rcpf(x); }
__device__ __forceinline__ float dot2(h2v a, h2v b, float c){
  return __builtin_amdgcn_fdot2(a, b, c, false);
}

#define LOG2E 1.4426950408889634f
#define LN2   0.6931471805599453f

__device__ __forceinline__ float fast_tanh(float x){
  float ax = fabsf(x);
  float e  = exp2f(ax * (-2.0f * LOG2E));
  float t  = (1.0f - e) * rcp_f(1.0f + e);
  return copysignf(t, x);
}
__device__ __forceinline__ float fast_sp(float x){
  float ax = fabsf(x);
  float e  = exp2f(ax * -LOG2E);
  return fmaxf(x, 0.0f) + log2f(1.0f + e) * LN2;
}
__device__ __forceinline__ float fast_sig(float x){
  float ax = fabsf(x);
  float e  = exp2f(ax * -LOG2E);
  float r  = rcp_f(1.0f + e);
  return x >= 0.0f ? r : e * r;
}
__device__ __forceinline__ float sig_from_sp(float sp){
  return 1.0f - exp2f(sp * -LOG2E);
}
__device__ __forceinline__ h2v mkh2(float a, float b){
  h2v r; r.x = (_Float16)a; r.y = (_Float16)b; return r;
}
__device__ __forceinline__ uint packh(float a, float b){
  ushort lo = __builtin_bit_cast(ushort, (_Float16)a);
  ushort hi = __builtin_bit_cast(ushort, (_Float16)b);
  return (uint)lo | ((uint)hi << 16);
}
__device__ __forceinline__ float f16lo(uint u){
  return (float)__builtin_bit_cast(_Float16, (ushort)(u & 0xffffu));
}
__device__ __forceinline__ float f16hi(uint u){
  return (float)__builtin_bit_cast(_Float16, (ushort)(u >> 16));
}

// ================= fused kernel: stage + pack + yref + compute =================
// R5 structure (best measured: 183 us graph): FNN L2 via MFMA, ICNN on dot2
// with h2v LDS weights, launch_bounds(512,2) -> 128-VGPR cap, VGPR=124 no spill.
// Only change vs R5: mt==6 epilogue trim (acc rows 200-223 are zero padding ->
// regs 4..15 contribute exactly 0; skipping is bitwise-identical).
__global__ __launch_bounds__(512, 2) void holo_main(
    const float* __restrict__ X, const float* __restrict__ U,
    const float* __restrict__ xref,
    const float* __restrict__ fw1, const float* __restrict__ fb1,
    const float* __restrict__ fw2, const float* __restrict__ fb2,
    const float* __restrict__ fw3, const float* __restrict__ fb3,
    const float* __restrict__ gw,  const float* __restrict__ gb,
    const float* __restrict__ iw1, const float* __restrict__ ib1,
    const float* __restrict__ iw2, const float* __restrict__ ib2,
    const float* __restrict__ iw3, const float* __restrict__ ib3,
    const float* __restrict__ iw4, const float* __restrict__ ib4,
    const float* __restrict__ im2, const float* __restrict__ im3,
    const float* __restrict__ im4,
    float* __restrict__ out, int N)
{
  // ---- LDS ----
  __shared__ ushort sW2r[224*84];            // fw2 MFMA-A [224 rows][84 halves]
  __shared__ uint4  sW3r[224];               // per neuron n: fw3 d-pairs + fb2[n]
  __shared__ h2v sPW1[240];    // fw1 [80][3]
  __shared__ h2v sPG[108];     // gw  [36][3]
  __shared__ h2v sPI1[180];    // iw1 [60][3]
  __shared__ h2v sPI1C[180];   // iw1^T pairs: [30 k1-pairs][6]
  __shared__ h2v sPI3[900];    // iw3 [30][30 j-pairs]
  __shared__ h2v sPI3C[900];   // iw3^T pairs: [60 j][15 i3-pairs]
  __shared__ h2v sPM2[180];    // im2 [60][3]
  __shared__ h2v sPM2C[180];   // im2^T pairs: [30 j-pairs][6]
  __shared__ h2v sPM3[90];     // im3 [30][3]
  __shared__ h2v sPM3C[90];    // im3^T pairs: [15 i3-pairs][6]
  __shared__ h2v sPM4[4];      // im4 [3]
  __shared__ h2v sPI2T[1800];  // iw2 transposed stream: [30 k1-pairs][60 j]
  __shared__ h2v sPI2C[1800];  // iw2 col pairs: [60 k1][30 j-pairs]
  __shared__ float sFB1[80], sFB3[6], sGB[36];
  __shared__ float sIB1[60], sIB2[60], sIB3[30], sIW4[30], sIM4[6], sXREF[6];
  __shared__ float sS1[60], sS2[60], sS3[30];
  __shared__ float sYREF, sIB4;

  const int t = threadIdx.x;
  const int T = 512;
  const int lane = t & 63;

  // ---- stage + pack from original weights ----
  for (int idx=t; idx<224*42; idx+=T){          // sW2r as u32 pairs
    int row = idx/42, c = idx%42, k = 2*c;
    uint v = 0;
    if (row < 200 && k < 80) v = packh(fw2[row*80+k], fw2[row*80+k+1]);
    ((uint*)sW2r)[idx] = v;
  }
  for (int n=t; n<224; n+=T){                   // sW3r epilogue table
    uint4 v = {0u,0u,0u,0u};
    if (n < 200){
      v.x = packh(fw3[0*200+n], fw3[1*200+n]);
      v.y = packh(fw3[2*200+n], fw3[3*200+n]);
      v.z = packh(fw3[4*200+n], fw3[5*200+n]);
      v.w = __builtin_bit_cast(uint, fb2[n]);
    }
    sW3r[n] = v;
  }
  for (int i=t;i<240;i+=T){ int o=i/3,p=i%3; sPW1[i]=mkh2(fw1[o*6+2*p],fw1[o*6+2*p+1]); }
  for (int i=t;i<108;i+=T){ int o=i/3,p=i%3; sPG[i]=mkh2(gw[o*6+2*p],gw[o*6+2*p+1]); }
  for (int i=t;i<180;i+=T){ int o=i/3,p=i%3; sPI1[i]=mkh2(iw1[o*6+2*p],iw1[o*6+2*p+1]); }
  for (int i=t;i<180;i+=T){ int q=i/6,d=i%6; sPI1C[i]=mkh2(iw1[(2*q)*6+d],iw1[(2*q+1)*6+d]); }
  for (int i=t;i<900;i+=T){ int r=i/30,q=i%30; sPI3[i]=mkh2(iw3[r*60+2*q],iw3[r*60+2*q+1]); }
  for (int i=t;i<900;i+=T){ int j=i/15,q=i%15; sPI3C[i]=mkh2(iw3[(2*q)*60+j],iw3[(2*q+1)*60+j]); }
  for (int i=t;i<180;i+=T){ int j=i/3,p=i%3; sPM2[i]=mkh2(im2[j*6+2*p],im2[j*6+2*p+1]); }
  for (int i=t;i<180;i+=T){ int q=i/6,d=i%6; sPM2C[i]=mkh2(im2[(2*q)*6+d],im2[(2*q+1)*6+d]); }
  for (int i=t;i<90;i+=T){ int r=i/3,p=i%3; sPM3[i]=mkh2(im3[r*6+2*p],im3[r*6+2*p+1]); }
  for (int i=t;i<90;i+=T){ int q=i/6,d=i%6; sPM3C[i]=mkh2(im3[(2*q)*6+d],im3[(2*q+1)*6+d]); }
  for (int i=t;i<3;i+=T) sPM4[i]=mkh2(im4[2*i],im4[2*i+1]);
  for (int i=t;i<1800;i+=T){ int p=i/60,j=i%60; sPI2T[i]=mkh2(iw2[j*60+2*p],iw2[j*60+2*p+1]); }
  for (int i=t;i<1800;i+=T){ int k1=i/30,q=i%30; sPI2C[i]=mkh2(iw2[(2*q)*60+k1],iw2[(2*q+1)*60+k1]); }
  for (int k=t;k<80;k+=T) sFB1[k]=fb1[k];
  for (int k=t;k<6;k+=T){ sFB3[k]=fb3[k]; sIM4[k]=im4[k]; sXREF[k]=xref[k]; }
  for (int k=t;k<36;k+=T) sGB[k]=gb[k];
  for (int k=t;k<60;k+=T){ sIB1[k]=ib1[k]; sIB2[k]=ib2[k]; }
  for (int k=t;k<30;k+=T){ sIB3[k]=ib3[k]; sIW4[k]=iw4[k]; }
  if (t==0) sIB4=ib4[0];
  __syncthreads();

  // ---- cooperative yref = icnn(xref) using the SAME staged f16 weights ----
  {
    h2v xrp[3];
    #pragma unroll
    for (int p = 0; p < 3; p++) xrp[p] = mkh2(sXREF[2*p], sXREF[2*p+1]);
    if (t < 60){
      float z = sIB1[t];
      #pragma unroll
      for (int p = 0; p < 3; p++) z = dot2(sPI1[t*3+p], xrp[p], z);
      sS1[t] = fast_sp(z);
    }
    __syncthreads();
    if (t < 60){
      float z = sIB2[t];
      #pragma unroll
      for (int p = 0; p < 3; p++) z = dot2(sPM2[t*3+p], xrp[p], z);
      for (int p = 0; p < 30; p++)
        z = dot2(sPI2T[p*60+t], mkh2(sS1[2*p], sS1[2*p+1]), z);
      sS2[t] = fast_sp(z);
    }
    __syncthreads();
    if (t < 30){
      float z = sIB3[t];
      #pragma unroll
      for (int p = 0; p < 3; p++) z = dot2(sPM3[t*3+p], xrp[p], z);
      for (int q = 0; q < 30; q++)
        z = dot2(sPI3[t*30+q], mkh2(sS2[2*q], sS2[2*q+1]), z);
      sS3[t] = fast_sp(z);
    }
    __syncthreads();
    if (t == 0){
      float y = sIB4;
      #pragma unroll
      for (int p = 0; p < 3; p++) y = dot2(sPM4[p], xrp[p], y);
      for (int j = 0; j < 30; j++) y = fmaf(sIW4[j], sS3[j], y);
      sYREF = y;
    }
    __syncthreads();
  }

  // ---- per-thread sample compute (guarded loads/stores, full-wave execution) ----
  const int i = blockIdx.x * blockDim.x + t;
  const bool valid = (i < N);

  float x[6]; h2v xp[3];
  #pragma unroll
  for (int k = 0; k < 6; k++) x[k] = valid ? X[(long)i*6 + k] : 0.0f;
  #pragma unroll
  for (int p = 0; p < 3; p++) xp[p] = mkh2(x[2*p], x[2*p+1]);

  // ============ FNN layer 1: 6 -> 80, tanh (packed u32 pairs) ============
  uint h1u[40];
  #pragma unroll
  for (int o = 0; o < 80; o += 2){
    float z0 = sFB1[o], z1 = sFB1[o+1];
    #pragma unroll
    for (int p = 0; p < 3; p++){
      z0 = dot2(sPW1[o*3 + p],     xp[p], z0);
      z1 = dot2(sPW1[(o+1)*3 + p], xp[p], z1);
    }
    h1u[o/2] = packh(fast_tanh(z0), fast_tanh(z1));
  }

  // ============ FNN L2+L3 via MFMA (32x32x16 f16) ============
  // Per wave: C(200x64) = W2(200x80) . h1^T(80x64); 7 mt x 2 nt x 5 kt MFMAs.
  // A (W2): lane holds A[row = mt*32 + (lane&31)][k = kt*16 + 8*(lane>>5)+e]
  // B (h1): lane holds B[k = kt*16 + 8*(lane>>5)+e][col-sample = nt*32 + (lane&31)]
  // C:      col-sample = lane&31, row-neuron = (reg&3)+8*(reg>>2)+4*(lane>>5)
  const int hh = lane >> 5;
  const int l31 = lane & 31;

  // B-fragments from h1 via ds_bpermute (pull sample (nt*32+l31)'s h1 regs)
  uint bf0[5][4], bf1[5][4];
  {
    int a0 = 4 * l31;          // nt = 0
    int a1 = 4 * (32 + l31);   // nt = 1
    #pragma unroll
    for (int kt = 0; kt < 5; kt++){
      #pragma unroll
      for (int q = 0; q < 4; q++){
        int lo0 = __builtin_amdgcn_ds_bpermute(a0, (int)h1u[kt*8 + q]);
        int hi0 = __builtin_amdgcn_ds_bpermute(a0, (int)h1u[kt*8 + 4 + q]);
        bf0[kt][q] = hh ? (uint)hi0 : (uint)lo0;
        int lo1 = __builtin_amdgcn_ds_bpermute(a1, (int)h1u[kt*8 + q]);
        int hi1 = __builtin_amdgcn_ds_bpermute(a1, (int)h1u[kt*8 + 4 + q]);
        bf1[kt][q] = hh ? (uint)hi1 : (uint)lo1;
      }
    }
  }

  float fp0[6] = {0.f,0.f,0.f,0.f,0.f,0.f};
  float fp1[6] = {0.f,0.f,0.f,0.f,0.f,0.f};
  for (int mt = 0; mt < 7; mt++){
    const int row = mt*32 + l31;
    // A-fragments for all 5 k-tiles (2x ds_read_b64 each, 8B aligned)
    f16x8 af[5];
    #pragma unroll
    for (int kt = 0; kt < 5; kt++){
      const ushort* wp = &sW2r[row*84 + kt*16 + 8*hh];
      uint2 w0 = *(const uint2*)wp;
      uint2 w1 = *(const uint2*)(wp + 4);
      uint4 au; au.x = w0.x; au.y = w0.y; au.z = w1.x; au.w = w1.y;
      af[kt] = __builtin_bit_cast(f16x8, au);
    }
    f32x16 acc0 = {0,0,0,0,0,0,0,0,0,0,0,0,0,0,0,0};
    f32x16 acc1 = {0,0,0,0,0,0,0,0,0,0,0,0,0,0,0,0};
    #pragma unroll
    for (int kt = 0; kt < 5; kt++){
      uint4 b0u; b0u.x=bf0[kt][0]; b0u.y=bf0[kt][1]; b0u.z=bf0[kt][2]; b0u.w=bf0[kt][3];
      uint4 b1u; b1u.x=bf1[kt][0]; b1u.y=bf1[kt][1]; b1u.z=bf1[kt][2]; b1u.w=bf1[kt][3];
      acc0 = __builtin_amdgcn_mfma_f32_32x32x16_f16(af[kt], __builtin_bit_cast(f16x8, b0u), acc0, 0, 0, 0);
      acc1 = __builtin_amdgcn_mfma_f32_32x32x16_f16(af[kt], __builtin_bit_cast(f16x8, b1u), acc1, 0, 0, 0);
    }
    // epilogue: bias + tanh + W3 partial reduction (C layout verified m74/m101)
    // mt==6: neuron rows 200-223 are zero padding; only regs 0-3 map to n<200,
    // the rest contribute exactly 0 -> skip (bitwise-identical).
    #pragma unroll
    for (int reg = 0; reg < 16; reg++){
      if (mt == 6 && reg >= 4) continue;
      int n = mt*32 + (reg & 3) + 8*(reg >> 2) + 4*hh;
      uint4 w = sW3r[n];
      float bias = __builtin_bit_cast(float, w.w);
      float t0 = fast_tanh(acc0[reg] + bias);
      float t1 = fast_tanh(acc1[reg] + bias);
      float w0 = f16lo(w.x), w1 = f16hi(w.x);
      float w2 = f16lo(w.y), w3 = f16hi(w.y);
      float w4 = f16lo(w.z), w5 = f16hi(w.z);
      fp0[0] = fmaf(w0, t0, fp0[0]); fp1[0] = fmaf(w0, t1, fp1[0]);
      fp0[1] = fmaf(w1, t0, fp0[1]); fp1[1] = fmaf(w1, t1, fp1[1]);
      fp0[2] = fmaf(w2, t0, fp0[2]); fp1[2] = fmaf(w2, t1, fp1[2]);
      fp0[3] = fmaf(w3, t0, fp0[3]); fp1[3] = fmaf(w3, t1, fp1[3]);
      fp0[4] = fmaf(w4, t0, fp0[4]); fp1[4] = fmaf(w4, t1, fp1[4]);
      fp0[5] = fmaf(w5, t0, fp0[5]); fp1[5] = fmaf(w5, t1, fp1[5]);
    }
  }
  // merge lane halves (each sample's neuron-sum is split across lane and lane^32),
  // then keep the nt matching this lane's own sample (nt = lane>>5).
  float f[6];
  #pragma unroll
  for (int d = 0; d < 6; d++){
    float s0 = fp0[d] + __shfl_xor(fp0[d], 32, 64);
    float s1 = fp1[d] + __shfl_xor(fp1[d], 32, 64);
    f[d] = sFB3[d] + (hh ? s1 : s0);
  }

  // ============ ICNN forward ============
  float c2[60];
  #pragma unroll
  for (int j = 0; j < 60; j++){
    float z = sIB2[j];
    #pragma unroll
    for (int p = 0; p < 3; p++) z = dot2(sPM2[j*3 + p], xp[p], z);
    c2[j] = z;
  }
  for (int p = 0; p < 30; p++){           // k1 pairs, streamed
    float za = sIB1[2*p], zb = sIB1[2*p+1];
    #pragma unroll
    for (int q = 0; q < 3; q++){
      za = dot2(sPI1[(2*p)*3 + q],   xp[q], za);
      zb = dot2(sPI1[(2*p+1)*3 + q], xp[q], zb);
    }
    h2v s = mkh2(fast_sp(za), fast_sp(zb));
    #pragma unroll
    for (int j = 0; j < 60; j++) c2[j] = dot2(sPI2T[p*60 + j], s, c2[j]);
  }
  h2v c2p[30];
  #pragma unroll
  for (int j = 0; j < 60; j += 2)
    c2p[j/2] = mkh2(fast_sp(c2[j]), fast_sp(c2[j+1]));

  // layer 3 fwd + y + g3
  float y = sIB4;
  #pragma unroll
  for (int p = 0; p < 3; p++) y = dot2(sPM4[p], xp[p], y);
  float ac[6];
  #pragma unroll
  for (int d = 0; d < 6; d++) ac[d] = sIM4[d];
  float g3[30];
  #pragma unroll
  for (int i3 = 0; i3 < 30; i3++){
    float z = sIB3[i3];
    #pragma unroll
    for (int p = 0; p < 3; p++) z = dot2(sPM3[i3*3 + p], xp[p], z);
    #pragma unroll
    for (int q = 0; q < 30; q++) z = dot2(sPI3[i3*30 + q], c2p[q], z);
    float sp3 = fast_sp(z);
    float w4  = sIW4[i3];
    y = fmaf(w4, sp3, y);
    g3[i3] = w4 * sig_from_sp(sp3);
  }
  h2v g3p[15];
  #pragma unroll
  for (int q = 0; q < 15; q++) g3p[q] = mkh2(g3[2*q], g3[2*q+1]);
  #pragma unroll
  for (int q = 0; q < 15; q++){
    #pragma unroll
    for (int d = 0; d < 6; d++) ac[d] = dot2(sPM3C[q*6 + d], g3p[q], ac[d]);
  }

  // bwd g2
  h2v g2p[30];
  #pragma unroll
  for (int j = 0; j < 60; j += 2){
    float ta = 0.0f, tb = 0.0f;
    #pragma unroll
    for (int q = 0; q < 15; q++){
      ta = dot2(sPI3C[j*15 + q],     g3p[q], ta);
      tb = dot2(sPI3C[(j+1)*15 + q], g3p[q], tb);
    }
    h2v sp = c2p[j/2];
    ta *= sig_from_sp((float)sp.x);
    tb *= sig_from_sp((float)sp.y);
    h2v tp = mkh2(ta, tb);
    g2p[j/2] = tp;
    #pragma unroll
    for (int d = 0; d < 6; d++) ac[d] = dot2(sPM2C[(j/2)*6 + d], tp, ac[d]);
  }

  // bwd g1 (streamed; z1 recomputed)
  for (int p = 0; p < 30; p++){
    float za = sIB1[2*p], zb = sIB1[2*p+1];
    #pragma unroll
    for (int q = 0; q < 3; q++){
      za = dot2(sPI1[(2*p)*3 + q],   xp[q], za);
      zb = dot2(sPI1[(2*p+1)*3 + q], xp[q], zb);
    }
    float ta = 0.0f, tb = 0.0f;
    #pragma unroll
    for (int q = 0; q < 30; q++){
      ta = dot2(sPI2C[(2*p)*30 + q],   g2p[q], ta);
      tb = dot2(sPI2C[(2*p+1)*30 + q], g2p[q], tb);
    }
    ta *= fast_sig(za); tb *= fast_sig(zb);
    h2v tp = mkh2(ta, tb);
    #pragma unroll
    for (int d = 0; d < 6; d++) ac[d] = dot2(sPI1C[p*6 + d], tp, ac[d]);
  }

  // ============ V, dV ============
  float hdiff = y - sYREF;
  float sigma = (hdiff >= 1.0f) ? (hdiff - 0.5f) : ((hdiff > 0.0f) ? 0.5f*hdiff*hdiff : 0.0f);
  float sigp  = (hdiff >= 1.0f) ? 1.0f          : ((hdiff > 0.0f) ? hdiff             : 0.0f);
  float dx2 = 0.0f;
  float dV[6];
  #pragma unroll
  for (int d = 0; d < 6; d++){
    float dx = x[d] - sXREF[d];
    dx2 = fmaf(dx, dx, dx2);
    dV[d] = fmaf(sigp, ac[d], 2.0f*EPS*dx);
  }
  float V = sigma + EPS*dx2;

  float sc = ALPHA * V;
  #pragma unroll
  for (int d = 0; d < 6; d++) sc = fmaf(dV[d], f[d], sc);

  // ============ GNN + combine ============
  float u[6];
  #pragma unroll
  for (int m = 0; m < 6; m++) u[m] = valid ? U[(long)i*6 + m] : 0.0f;
  float am[6] = {0.f,0.f,0.f,0.f,0.f,0.f};
  float gU[6];
  #pragma unroll
  for (int d = 0; d < 6; d++){
    float acc = 0.0f;
    #pragma unroll
    for (int m = 0; m < 6; m++){
      int o = d*6 + m;
      float g = sGB[o];
      #pragma unroll
      for (int p = 0; p < 3; p++) g = dot2(sPG[o*3 + p], xp[p], g);
      am[m] = fmaf(dV[d], g, am[m]);
      acc   = fmaf(g, u[m], acc);
    }
    gU[d] = acc;
  }
  #pragma unroll
  for (int m = 0; m < 6; m++) sc -= fabsf(am[m]);

  float n2 = 0.0f;
  #pragma unroll
  for (int d = 0; d < 6; d++) n2 = fmaf(dV[d], dV[d], n2);
  float r = fmaxf(sc, 0.0f) * rcp_f(n2);

  if (valid){
    #pragma unroll
    for (int d = 0; d < 6; d++)
      out[(long)i*6 + d] = f[d] - dV[d]*r + gU[d];
  }
}

extern "C" void kernel_launch(void* const* d_in, const int* in_sizes, int n_in,
                              void* d_out, int out_size, void* d_ws, size_t ws_size,
                              hipStream_t stream)
{
  const float* X    = (const float*)d_in[0];
  const float* U    = (const float*)d_in[1];
  const float* xref = (const float*)d_in[2];
  const float* fw1  = (const float*)d_in[3];
  const float* fb1  = (const float*)d_in[4];
  const float* fw2  = (const float*)d_in[5];
  const float* fb2  = (const float*)d_in[6];
  const float* fw3  = (const float*)d_in[7];
  const float* fb3  = (const float*)d_in[8];
  const float* gw   = (const float*)d_in[9];
  const float* gb   = (const float*)d_in[10];
  const float* iw1  = (const float*)d_in[11];
  const float* ib1  = (const float*)d_in[12];
  const float* iw2  = (const float*)d_in[13];
  const float* ib2  = (const float*)d_in[14];
  const float* iw3  = (const float*)d_in[15];
  const float* ib3  = (const float*)d_in[16];
  const float* iw4  = (const float*)d_in[17];
  const float* ib4  = (const float*)d_in[18];
  const float* im2  = (const float*)d_in[19];
  const float* im3  = (const float*)d_in[20];
  const float* im4  = (const float*)d_in[21];

  float* out = (float*)d_out;
  int N = in_sizes[0] / 6;

  int threads = 512;
  int blocks  = (N + threads - 1) / threads;
  holo_main<<<blocks, threads, 0, stream>>>(X, U, xref,
      fw1, fb1, fw2, fb2, fw3, fb3, gw, gb,
      iw1, ib1, iw2, ib2, iw3, ib3, iw4, ib4, im2, im3, im4,
      out, N);
}